// Round 1
// baseline (547.320 us; speedup 1.0000x reference)
//
#include <hip/hip_runtime.h>

#define B   8
#define C   256
#define N   4096
#define H   8
#define D   64
#define HID 512
#define MC  8      // m-chunks for kernel 1 partials
#define MCH 512    // N / MC
#define SCALE 0.125f

// ---------------------------------------------------------------------------
// Kernel 1: K/V projection + exp + partial ctx/Z per (b, h, m-chunk)
//   K_h = Wk_h (64x256) @ C_b (256 x m)   (same for V)
//   ctx_part[d][e] = sum_m exp(K[d][m]) * V[e][m],  z_part[d] = sum_m exp(K[d][m])
// ---------------------------------------------------------------------------
__global__ __launch_bounds__(256, 2) void kv_ctx_kernel(
    const float* __restrict__ ctxt,      // [B][C][N]
    const float* __restrict__ Wk,        // [HID][C]
    const float* __restrict__ Wv,        // [HID][C]
    float* __restrict__ ctx_part,        // [B][H][MC][D][D]
    float* __restrict__ z_part)          // [B][H][MC][D]
{
  const int mc = blockIdx.x, h = blockIdx.y, b = blockIdx.z;
  const int tid = threadIdx.x;
  const int tx = tid & 15, ty = tid >> 4;

  __shared__ float smem[2 * 64 * 68];
  float* wk_s = smem;                 // [16][68] (c-chunk x d)
  float* wv_s = smem + 16 * 68;       // [16][68]
  float* c_s  = smem + 32 * 68;       // [16][68] (c-chunk x m)
  float* p_s  = smem;                 // [64][68] (d x m)  -- phase B alias
  float* v_s  = smem + 64 * 68;       // [64][68] (e x m)

  float ctxa[4][4] = {{0.f}};
  float zacc = 0.f;

  for (int st = 0; st < 8; ++st) {
    const int m0 = mc * MCH + st * 64;
    float kacc[4][4] = {{0.f}};
    float vacc[4][4] = {{0.f}};

    for (int c0 = 0; c0 < C; c0 += 16) {
      __syncthreads();  // protect previous-phase LDS reads
      {
        const int d = tid >> 2, coff = (tid & 3) << 2;
        const float4 wk4 = *(const float4*)(Wk + (size_t)(h * 64 + d) * C + c0 + coff);
        const float4 wv4 = *(const float4*)(Wv + (size_t)(h * 64 + d) * C + c0 + coff);
        wk_s[(coff + 0) * 68 + d] = wk4.x;
        wk_s[(coff + 1) * 68 + d] = wk4.y;
        wk_s[(coff + 2) * 68 + d] = wk4.z;
        wk_s[(coff + 3) * 68 + d] = wk4.w;
        wv_s[(coff + 0) * 68 + d] = wv4.x;
        wv_s[(coff + 1) * 68 + d] = wv4.y;
        wv_s[(coff + 2) * 68 + d] = wv4.z;
        wv_s[(coff + 3) * 68 + d] = wv4.w;
        const int cc = tid >> 4, mo = (tid & 15) << 2;
        *(float4*)(c_s + cc * 68 + mo) =
            *(const float4*)(ctxt + ((size_t)b * C + c0 + cc) * N + m0 + mo);
      }
      __syncthreads();
#pragma unroll
      for (int kc = 0; kc < 16; ++kc) {
        const float4 ak = *(const float4*)(wk_s + kc * 68 + ty * 4);
        const float4 av = *(const float4*)(wv_s + kc * 68 + ty * 4);
        const float4 bx = *(const float4*)(c_s + kc * 68 + tx * 4);
        const float b0 = bx.x, b1 = bx.y, b2 = bx.z, b3 = bx.w;
        kacc[0][0] += ak.x * b0; kacc[0][1] += ak.x * b1; kacc[0][2] += ak.x * b2; kacc[0][3] += ak.x * b3;
        kacc[1][0] += ak.y * b0; kacc[1][1] += ak.y * b1; kacc[1][2] += ak.y * b2; kacc[1][3] += ak.y * b3;
        kacc[2][0] += ak.z * b0; kacc[2][1] += ak.z * b1; kacc[2][2] += ak.z * b2; kacc[2][3] += ak.z * b3;
        kacc[3][0] += ak.w * b0; kacc[3][1] += ak.w * b1; kacc[3][2] += ak.w * b2; kacc[3][3] += ak.w * b3;
        vacc[0][0] += av.x * b0; vacc[0][1] += av.x * b1; vacc[0][2] += av.x * b2; vacc[0][3] += av.x * b3;
        vacc[1][0] += av.y * b0; vacc[1][1] += av.y * b1; vacc[1][2] += av.y * b2; vacc[1][3] += av.y * b3;
        vacc[2][0] += av.z * b0; vacc[2][1] += av.z * b1; vacc[2][2] += av.z * b2; vacc[2][3] += av.z * b3;
        vacc[3][0] += av.w * b0; vacc[3][1] += av.w * b1; vacc[3][2] += av.w * b2; vacc[3][3] += av.w * b3;
      }
    }

    __syncthreads();  // done reading phase-A buffers
#pragma unroll
    for (int i = 0; i < 4; ++i) {
      float4 pe, ve;
      pe.x = __expf(kacc[i][0]); pe.y = __expf(kacc[i][1]);
      pe.z = __expf(kacc[i][2]); pe.w = __expf(kacc[i][3]);
      ve.x = vacc[i][0]; ve.y = vacc[i][1]; ve.z = vacc[i][2]; ve.w = vacc[i][3];
      *(float4*)(p_s + (ty * 4 + i) * 68 + tx * 4) = pe;
      *(float4*)(v_s + (ty * 4 + i) * 68 + tx * 4) = ve;
    }
    __syncthreads();

#pragma unroll 4
    for (int mq = 0; mq < 16; ++mq) {
      float4 pr[4], vr[4];
#pragma unroll
      for (int i = 0; i < 4; ++i) {
        pr[i] = *(const float4*)(p_s + (ty * 4 + i) * 68 + mq * 4);
        vr[i] = *(const float4*)(v_s + (tx * 4 + i) * 68 + mq * 4);
      }
#pragma unroll
      for (int i = 0; i < 4; ++i)
#pragma unroll
        for (int j = 0; j < 4; ++j)
          ctxa[i][j] += pr[i].x * vr[j].x + pr[i].y * vr[j].y +
                        pr[i].z * vr[j].z + pr[i].w * vr[j].w;
    }

    if (tid < 64) {  // Z partial for row d = tid
      float s = 0.f;
#pragma unroll
      for (int mq = 0; mq < 16; ++mq) {
        const float4 pv = *(const float4*)(p_s + tid * 68 + mq * 4);
        s += pv.x + pv.y + pv.z + pv.w;
      }
      zacc += s;
    }
  }

  float* cp = ctx_part + ((((size_t)b * H + h) * MC + mc) << 12);
#pragma unroll
  for (int i = 0; i < 4; ++i) {
    float4 r;
    r.x = ctxa[i][0]; r.y = ctxa[i][1]; r.z = ctxa[i][2]; r.w = ctxa[i][3];
    *(float4*)(cp + (ty * 4 + i) * 64 + tx * 4) = r;
  }
  if (tid < 64) z_part[(((b * H + h) * MC + mc) << 6) + tid] = zacc;
}

// ---------------------------------------------------------------------------
// Kernel 2: combine partials, normalize rows by Z, fold in scale
// ---------------------------------------------------------------------------
__global__ __launch_bounds__(256) void combine_kernel(
    const float* __restrict__ ctx_part, const float* __restrict__ z_part,
    float* __restrict__ ctxn)            // [B*H][D][D]
{
  const int bh = blockIdx.x, tid = threadIdx.x;
  __shared__ float zs[64];
  if (tid < 64) {
    float z = 0.f;
    for (int p = 0; p < MC; ++p) z += z_part[((bh * MC + p) << 6) + tid];
    zs[tid] = SCALE / z;
  }
  __syncthreads();
  for (int k = 0; k < 16; ++k) {
    const int idx = tid + (k << 8);
    float s = 0.f;
    for (int p = 0; p < MC; ++p) s += ctx_part[(((size_t)bh * MC + p) << 12) + idx];
    ctxn[((size_t)bh << 12) + idx] = s * zs[idx >> 6];
  }
}

// ---------------------------------------------------------------------------
// Kernel 3a: A[b][h*64+e][c] = sum_d ctxn[b,h,d,e] * Wq[h*64+d, c]
// ---------------------------------------------------------------------------
__global__ __launch_bounds__(256) void a_kernel(
    const float* __restrict__ ctxn, const float* __restrict__ Wq,
    float* __restrict__ A)               // [B][HID][C]
{
  const int bh = blockIdx.x, tid = threadIdx.x;
  const int b = bh >> 3, h = bh & 7;
  __shared__ float ct[64 * 65];   // [d][e]
  __shared__ float wq[64 * 68];   // [d][c-tile]
  for (int r = 0; r < 16; ++r) {
    const int idx = tid + (r << 8);
    ct[(idx >> 6) * 65 + (idx & 63)] = ctxn[((size_t)bh << 12) + idx];
  }
  const int e = tid & 63, co = tid >> 6;
  for (int cti = 0; cti < 4; ++cti) {
    const int c0 = cti << 6;
    __syncthreads();
    for (int r = 0; r < 16; ++r) {
      const int idx = tid + (r << 8);
      wq[(idx >> 6) * 68 + (idx & 63)] =
          Wq[(size_t)(h * 64 + (idx >> 6)) * C + c0 + (idx & 63)];
    }
    __syncthreads();
    float acc[16];
#pragma unroll
    for (int k = 0; k < 16; ++k) acc[k] = 0.f;
    for (int d = 0; d < 64; ++d) {
      const float cv = ct[d * 65 + e];
      const float* wr = wq + d * 68 + co * 16;
#pragma unroll
      for (int k = 0; k < 16; ++k) acc[k] += cv * wr[k];
    }
    float* Ar = A + ((size_t)b * HID + h * 64 + e) * C + c0 + co * 16;
#pragma unroll
    for (int k = 0; k < 16; ++k) Ar[k] = acc[k];
  }
}

// ---------------------------------------------------------------------------
// Kernel 3b: M[b] = Wo (256x512) @ A[b] (512x256)
// ---------------------------------------------------------------------------
__global__ __launch_bounds__(256) void m_kernel(
    const float* __restrict__ A, const float* __restrict__ Wo,
    float* __restrict__ Mm)              // [B][C][C]
{
  const int tile = blockIdx.x, b = blockIdx.y;
  const int o0 = (tile & 3) << 6, c0 = (tile >> 2) << 6;
  const int tid = threadIdx.x, tx = tid & 15, ty = tid >> 4;
  __shared__ float wo_s[16 * 68];  // [k][o]
  __shared__ float a_s[16 * 68];   // [k][c]
  float acc[4][4] = {{0.f}};
  for (int k0 = 0; k0 < HID; k0 += 16) {
    __syncthreads();
    {
      const int o = tid >> 2, koff = (tid & 3) << 2;
      const float4 w4 = *(const float4*)(Wo + (size_t)(o0 + o) * HID + k0 + koff);
      wo_s[(koff + 0) * 68 + o] = w4.x;
      wo_s[(koff + 1) * 68 + o] = w4.y;
      wo_s[(koff + 2) * 68 + o] = w4.z;
      wo_s[(koff + 3) * 68 + o] = w4.w;
      const int kk = tid >> 4, cc = (tid & 15) << 2;
      *(float4*)(a_s + kk * 68 + cc) =
          *(const float4*)(A + ((size_t)b * HID + k0 + kk) * C + c0 + cc);
    }
    __syncthreads();
#pragma unroll
    for (int kc = 0; kc < 16; ++kc) {
      const float4 wv = *(const float4*)(wo_s + kc * 68 + ty * 4);
      const float4 av = *(const float4*)(a_s + kc * 68 + tx * 4);
      const float b0 = av.x, b1 = av.y, b2 = av.z, b3 = av.w;
      acc[0][0] += wv.x * b0; acc[0][1] += wv.x * b1; acc[0][2] += wv.x * b2; acc[0][3] += wv.x * b3;
      acc[1][0] += wv.y * b0; acc[1][1] += wv.y * b1; acc[1][2] += wv.y * b2; acc[1][3] += wv.y * b3;
      acc[2][0] += wv.z * b0; acc[2][1] += wv.z * b1; acc[2][2] += wv.z * b2; acc[2][3] += wv.z * b3;
      acc[3][0] += wv.w * b0; acc[3][1] += wv.w * b1; acc[3][2] += wv.w * b2; acc[3][3] += wv.w * b3;
    }
  }
#pragma unroll
  for (int i = 0; i < 4; ++i) {
    float4 r;
    r.x = acc[i][0]; r.y = acc[i][1]; r.z = acc[i][2]; r.w = acc[i][3];
    *(float4*)(Mm + ((size_t)b * C + o0 + ty * 4 + i) * C + c0 + tx * 4) = r;
  }
}

// ---------------------------------------------------------------------------
// Kernel 4: out[b] = M[b] (256x256) @ X[b] (256x4096) + bo
// ---------------------------------------------------------------------------
__global__ __launch_bounds__(256) void out_kernel(
    const float* __restrict__ Mm, const float* __restrict__ x,
    const float* __restrict__ bo, float* __restrict__ out)
{
  const int nt = blockIdx.x, ot = blockIdx.y, b = blockIdx.z;
  const int o0 = ot << 6, n0 = nt << 6;
  const int tid = threadIdx.x, tx = tid & 15, ty = tid >> 4;
  __shared__ float m_s[16 * 68];  // [c][o]
  __shared__ float x_s[16 * 68];  // [c][n]
  float acc[4][4] = {{0.f}};
  for (int c0 = 0; c0 < C; c0 += 16) {
    __syncthreads();
    {
      const int o = tid >> 2, koff = (tid & 3) << 2;
      const float4 m4 = *(const float4*)(Mm + ((size_t)b * C + o0 + o) * C + c0 + koff);
      m_s[(koff + 0) * 68 + o] = m4.x;
      m_s[(koff + 1) * 68 + o] = m4.y;
      m_s[(koff + 2) * 68 + o] = m4.z;
      m_s[(koff + 3) * 68 + o] = m4.w;
      const int cc = tid >> 4, nn = (tid & 15) << 2;
      *(float4*)(x_s + cc * 68 + nn) =
          *(const float4*)(x + ((size_t)b * C + c0 + cc) * N + n0 + nn);
    }
    __syncthreads();
#pragma unroll
    for (int kc = 0; kc < 16; ++kc) {
      const float4 wv = *(const float4*)(m_s + kc * 68 + ty * 4);
      const float4 xv = *(const float4*)(x_s + kc * 68 + tx * 4);
      const float b0 = xv.x, b1 = xv.y, b2 = xv.z, b3 = xv.w;
      acc[0][0] += wv.x * b0; acc[0][1] += wv.x * b1; acc[0][2] += wv.x * b2; acc[0][3] += wv.x * b3;
      acc[1][0] += wv.y * b0; acc[1][1] += wv.y * b1; acc[1][2] += wv.y * b2; acc[1][3] += wv.y * b3;
      acc[2][0] += wv.z * b0; acc[2][1] += wv.z * b1; acc[2][2] += wv.z * b2; acc[2][3] += wv.z * b3;
      acc[3][0] += wv.w * b0; acc[3][1] += wv.w * b1; acc[3][2] += wv.w * b2; acc[3][3] += wv.w * b3;
    }
  }
#pragma unroll
  for (int i = 0; i < 4; ++i) {
    const float bias = bo[o0 + ty * 4 + i];
    float4 r;
    r.x = acc[i][0] + bias; r.y = acc[i][1] + bias;
    r.z = acc[i][2] + bias; r.w = acc[i][3] + bias;
    *(float4*)(out + ((size_t)b * C + o0 + ty * 4 + i) * N + n0 + tx * 4) = r;
  }
}

// ---------------------------------------------------------------------------
extern "C" void kernel_launch(void* const* d_in, const int* in_sizes, int n_in,
                              void* d_out, int out_size, void* d_ws, size_t ws_size,
                              hipStream_t stream) {
  const float* x    = (const float*)d_in[0];
  const float* ctxt = (const float*)d_in[1];
  const float* Wq   = (const float*)d_in[2];
  const float* Wk   = (const float*)d_in[3];
  const float* Wv   = (const float*)d_in[4];
  const float* Wo   = (const float*)d_in[5];
  const float* bo   = (const float*)d_in[6];
  float* out = (float*)d_out;

  float* ws = (float*)d_ws;
  float* ctx_part = ws;                                      // B*H*MC*D*D = 2097152
  float* z_part   = ctx_part + (size_t)B * H * MC * D * D;   // B*H*MC*D   = 32768
  float* ctxn     = z_part + (size_t)B * H * MC * D;         // B*H*D*D    = 262144
  float* A        = ctxn + (size_t)B * H * D * D;            // B*HID*C    = 1048576
  float* Mm       = A + (size_t)B * HID * C;                 // B*C*C      = 524288

  kv_ctx_kernel<<<dim3(MC, H, B), 256, 0, stream>>>(ctxt, Wk, Wv, ctx_part, z_part);
  combine_kernel<<<dim3(B * H), 256, 0, stream>>>(ctx_part, z_part, ctxn);
  a_kernel<<<dim3(B * H), 256, 0, stream>>>(ctxn, Wq, A);
  m_kernel<<<dim3(16, B), 256, 0, stream>>>(A, Wo, Mm);
  out_kernel<<<dim3(64, 4, B), 256, 0, stream>>>(Mm, x, bo, out);
}

// Round 2
// 303.933 us; speedup vs baseline: 1.8008x; 1.8008x over previous
//
#include <hip/hip_runtime.h>

#define B   8
#define C   256
#define N   4096
#define H   8
#define D   64
#define HID 512
#define SCALE 0.125f

typedef __attribute__((ext_vector_type(8))) __bf16 bf16x8;
typedef __attribute__((ext_vector_type(4))) float f32x4;

__device__ __forceinline__ ushort f2bf(float f) {
  union { float f; unsigned u; } v; v.f = f;
  unsigned r = v.u + 0x7FFFu + ((v.u >> 16) & 1u);
  return (ushort)(r >> 16);
}

__device__ __forceinline__ f32x4 mfma16(bf16x8 a, bf16x8 b, f32x4 c) {
  return __builtin_amdgcn_mfma_f32_16x16x32_bf16(a, b, c, 0, 0, 0);
}

// ---------------------------------------------------------------------------
// Cast Wk, Wv to bf16 (row-major [HID][C] kept).
// ---------------------------------------------------------------------------
__global__ __launch_bounds__(256) void cast_w_kernel(
    const float* __restrict__ Wk, const float* __restrict__ Wv,
    ushort* __restrict__ wk_bf, ushort* __restrict__ wv_bf) {
  const int t = (blockIdx.x * 256 + threadIdx.x) * 4;   // HID*C = 131072 elems
  const float4 a = *(const float4*)(Wk + t);
  const float4 b = *(const float4*)(Wv + t);
  ushort4 ra, rb;
  ra.x = f2bf(a.x); ra.y = f2bf(a.y); ra.z = f2bf(a.z); ra.w = f2bf(a.w);
  rb.x = f2bf(b.x); rb.y = f2bf(b.y); rb.z = f2bf(b.z); rb.w = f2bf(b.w);
  *(ushort4*)(wk_bf + t) = ra;
  *(ushort4*)(wv_bf + t) = rb;
}

// ---------------------------------------------------------------------------
// Transpose+cast: src fp32 [b][R][L] -> dst bf16 [b][L][R].  64x64 tiles.
// ---------------------------------------------------------------------------
__global__ __launch_bounds__(256) void transpose_cast_kernel(
    const float* __restrict__ src, ushort* __restrict__ dst, int R, int L) {
  __shared__ float tile[64 * 65];
  const int l0 = blockIdx.x * 64, r0 = blockIdx.y * 64, b = blockIdx.z;
  const int tid = threadIdx.x;
  const int rr = tid >> 4, c4 = (tid & 15) << 2;
  const float* sp = src + ((size_t)b * R + r0) * L + l0;
#pragma unroll
  for (int p = 0; p < 4; ++p) {
    const float4 v = *(const float4*)(sp + (size_t)(rr + p * 16) * L + c4);
    float* tp = tile + (rr + p * 16) * 65 + c4;
    tp[0] = v.x; tp[1] = v.y; tp[2] = v.z; tp[3] = v.w;
  }
  __syncthreads();
  const int lr = tid >> 2, rb = (tid & 3) << 4;
  uint pk[8];
#pragma unroll
  for (int k = 0; k < 16; k += 2) {
    const uint lo = f2bf(tile[(rb + k) * 65 + lr]);
    const uint hi = f2bf(tile[(rb + k + 1) * 65 + lr]);
    pk[k >> 1] = lo | (hi << 16);
  }
  ushort* dp = dst + ((size_t)b * L + l0 + lr) * R + r0 + rb;
  *(uint4*)dp = *(uint4*)pk;
  *(uint4*)(dp + 8) = *(uint4*)(pk + 4);
}

// ---------------------------------------------------------------------------
// Kernel 1 (MFMA): per (m-chunk of 256, h, b):
//   K = Wk_h @ C_b, P = exp(K); V = Wv_h @ C_b; ctx += P V^T; Z += rowsum(P)
// Each wave owns a 64-m quarter end-to-end (no inter-wave dataflow until the
// final reduce).  P/V relayout via XOR-swizzled LDS (conflict-free b128).
// ---------------------------------------------------------------------------
__global__ __launch_bounds__(256) void kv_mfma_kernel(
    const ushort* __restrict__ ctxt_bf,   // [B][N][C] bf16
    const ushort* __restrict__ wk_bf,     // [HID][C]
    const ushort* __restrict__ wv_bf,
    float* __restrict__ ctx_acc,          // [B*H][64*64] (pre-zeroed, atomic)
    float* __restrict__ z_acc)            // [B*H][64]    (pre-zeroed, atomic)
{
  __shared__ __align__(16) ushort pv[2 * 64 * 256];   // P | V, 64 KB
  const int mt = blockIdx.x, h = blockIdx.y, b = blockIdx.z;
  const int tid = threadIdx.x;
  const int w = tid >> 6, lane = tid & 63;
  const int col = lane & 15, quad = lane >> 4;

  const size_t m_base = (size_t)mt * 256 + w * 64;
  const ushort* cb = ctxt_bf + ((size_t)b * N + m_base) * C + quad * 8;
  const ushort* ka = wk_bf + ((size_t)h * 64 + col) * C + quad * 8;
  const ushort* va = wv_bf + ((size_t)h * 64 + col) * C + quad * 8;

  const f32x4 z4 = {0.f, 0.f, 0.f, 0.f};

  // ---- K projection ----
  f32x4 kacc[4][4];
#pragma unroll
  for (int i = 0; i < 4; ++i)
#pragma unroll
    for (int j = 0; j < 4; ++j) kacc[i][j] = z4;
#pragma unroll
  for (int kk = 0; kk < 8; ++kk) {
    bf16x8 af[4], bfz[4];
#pragma unroll
    for (int i = 0; i < 4; ++i) af[i] = *(const bf16x8*)(ka + (size_t)(i * 16) * C + kk * 32);
#pragma unroll
    for (int j = 0; j < 4; ++j) bfz[j] = *(const bf16x8*)(cb + (size_t)(j * 16 + col) * C + kk * 32);
#pragma unroll
    for (int i = 0; i < 4; ++i)
#pragma unroll
      for (int j = 0; j < 4; ++j) kacc[i][j] = mfma16(af[i], bfz[j], kacc[i][j]);
  }

  // ---- exp, stage P (swizzled), Z partials ----
  float zp[4][4];
#pragma unroll
  for (int i = 0; i < 4; ++i)
#pragma unroll
    for (int r = 0; r < 4; ++r) zp[i][r] = 0.f;
#pragma unroll
  for (int i = 0; i < 4; ++i)
#pragma unroll
    for (int j = 0; j < 4; ++j) {
      const int ml = w * 64 + j * 16 + col;
#pragma unroll
      for (int r = 0; r < 4; ++r) {
        const float p = __expf(kacc[i][j][r]);
        zp[i][r] += p;
        const int dd = i * 16 + quad * 4 + r;
        pv[dd * 256 + ((((ml >> 3) ^ (dd & 7)) << 3) | (ml & 7))] = f2bf(p);
      }
    }
#pragma unroll
  for (int i = 0; i < 4; ++i)
#pragma unroll
    for (int r = 0; r < 4; ++r) {
      float s = zp[i][r];
      s += __shfl_xor(s, 1); s += __shfl_xor(s, 2);
      s += __shfl_xor(s, 4); s += __shfl_xor(s, 8);
      if (col == 0)
        atomicAdd(&z_acc[((size_t)b * H + h) * 64 + i * 16 + quad * 4 + r], s);
    }

  // ---- V projection ----
  f32x4 vacc[4][4];
#pragma unroll
  for (int i = 0; i < 4; ++i)
#pragma unroll
    for (int j = 0; j < 4; ++j) vacc[i][j] = z4;
#pragma unroll
  for (int kk = 0; kk < 8; ++kk) {
    bf16x8 af[4], bfz[4];
#pragma unroll
    for (int i = 0; i < 4; ++i) af[i] = *(const bf16x8*)(va + (size_t)(i * 16) * C + kk * 32);
#pragma unroll
    for (int j = 0; j < 4; ++j) bfz[j] = *(const bf16x8*)(cb + (size_t)(j * 16 + col) * C + kk * 32);
#pragma unroll
    for (int i = 0; i < 4; ++i)
#pragma unroll
      for (int j = 0; j < 4; ++j) vacc[i][j] = mfma16(af[i], bfz[j], vacc[i][j]);
  }
#pragma unroll
  for (int i = 0; i < 4; ++i)
#pragma unroll
    for (int j = 0; j < 4; ++j) {
      const int ml = w * 64 + j * 16 + col;
#pragma unroll
      for (int r = 0; r < 4; ++r) {
        const int ee = i * 16 + quad * 4 + r;
        pv[64 * 256 + ee * 256 + ((((ml >> 3) ^ (ee & 7)) << 3) | (ml & 7))] =
            f2bf(vacc[i][j][r]);
      }
    }

  __syncthreads();

  // ---- ctx = P V^T over this wave's 64 m ----
  f32x4 cacc[4][4];
#pragma unroll
  for (int i = 0; i < 4; ++i)
#pragma unroll
    for (int j = 0; j < 4; ++j) cacc[i][j] = z4;
#pragma unroll
  for (int kk = 0; kk < 2; ++kk) {
    const int mloc = w * 64 + kk * 32 + quad * 8;
    bf16x8 pa[4], vb[4];
#pragma unroll
    for (int i = 0; i < 4; ++i) {
      const int dd = i * 16 + col;
      pa[i] = *(const bf16x8*)(pv + dd * 256 + (((mloc >> 3) ^ (dd & 7)) << 3));
    }
#pragma unroll
    for (int j = 0; j < 4; ++j) {
      const int ee = j * 16 + col;
      vb[j] = *(const bf16x8*)(pv + 64 * 256 + ee * 256 + (((mloc >> 3) ^ (ee & 7)) << 3));
    }
#pragma unroll
    for (int i = 0; i < 4; ++i)
#pragma unroll
      for (int j = 0; j < 4; ++j) cacc[i][j] = mfma16(pa[i], vb[j], cacc[i][j]);
  }

  __syncthreads();
  float* red = (float*)pv;
  for (int ww = 0; ww < 4; ++ww) {
    if (w == ww) {
#pragma unroll
      for (int i = 0; i < 4; ++i)
#pragma unroll
        for (int j = 0; j < 4; ++j)
#pragma unroll
          for (int r = 0; r < 4; ++r) {
            const int idx = (i * 16 + quad * 4 + r) * 64 + j * 16 + col;
            if (ww == 0) red[idx] = cacc[i][j][r];
            else         red[idx] += cacc[i][j][r];
          }
    }
    __syncthreads();
  }
  float* gp = ctx_acc + ((size_t)b * H + h) * 4096;
  for (int t = tid; t < 4096; t += 256) atomicAdd(gp + t, red[t]);
}

// ---------------------------------------------------------------------------
// Kernel 2: normalize rows by Z, fold in scale
// ---------------------------------------------------------------------------
__global__ __launch_bounds__(256) void combine_kernel(
    const float* __restrict__ ctx_acc, const float* __restrict__ z_acc,
    float* __restrict__ ctxn)            // [B*H][D][D]
{
  const int bh = blockIdx.x, tid = threadIdx.x;
  __shared__ float zs[64];
  if (tid < 64) zs[tid] = SCALE / z_acc[bh * 64 + tid];
  __syncthreads();
  for (int k = 0; k < 16; ++k) {
    const int idx = tid + (k << 8);
    ctxn[((size_t)bh << 12) + idx] = ctx_acc[((size_t)bh << 12) + idx] * zs[idx >> 6];
  }
}

// ---------------------------------------------------------------------------
// Kernel 3a: A[b][h*64+e][c] = sum_d ctxn[b,h,d,e] * Wq[h*64+d, c]   (fp32)
// ---------------------------------------------------------------------------
__global__ __launch_bounds__(256) void a_kernel(
    const float* __restrict__ ctxn, const float* __restrict__ Wq,
    float* __restrict__ A)               // [B][HID][C]
{
  const int bh = blockIdx.x, tid = threadIdx.x;
  const int b = bh >> 3, h = bh & 7;
  __shared__ float ct[64 * 65];   // [d][e]
  __shared__ float wq[64 * 68];   // [d][c-tile]
  for (int r = 0; r < 16; ++r) {
    const int idx = tid + (r << 8);
    ct[(idx >> 6) * 65 + (idx & 63)] = ctxn[((size_t)bh << 12) + idx];
  }
  const int e = tid & 63, co = tid >> 6;
  for (int cti = 0; cti < 4; ++cti) {
    const int c0 = cti << 6;
    __syncthreads();
    for (int r = 0; r < 16; ++r) {
      const int idx = tid + (r << 8);
      wq[(idx >> 6) * 68 + (idx & 63)] =
          Wq[(size_t)(h * 64 + (idx >> 6)) * C + c0 + (idx & 63)];
    }
    __syncthreads();
    float acc[16];
#pragma unroll
    for (int k = 0; k < 16; ++k) acc[k] = 0.f;
    for (int d = 0; d < 64; ++d) {
      const float cv = ct[d * 65 + e];
      const float* wr = wq + d * 68 + co * 16;
#pragma unroll
      for (int k = 0; k < 16; ++k) acc[k] += cv * wr[k];
    }
    float* Ar = A + ((size_t)b * HID + h * 64 + e) * C + c0 + co * 16;
#pragma unroll
    for (int k = 0; k < 16; ++k) Ar[k] = acc[k];
  }
}

// ---------------------------------------------------------------------------
// Kernel 3b: M[b] = Wo (256x512) @ A[b] (512x256)  -> bf16 [b][o][c]
// ---------------------------------------------------------------------------
__global__ __launch_bounds__(256) void m_kernel(
    const float* __restrict__ A, const float* __restrict__ Wo,
    ushort* __restrict__ M_bf)
{
  const int tile = blockIdx.x, b = blockIdx.y;
  const int o0 = (tile & 3) << 6, c0 = (tile >> 2) << 6;
  const int tid = threadIdx.x, tx = tid & 15, ty = tid >> 4;
  __shared__ float wo_s[16 * 68];  // [k][o]
  __shared__ float a_s[16 * 68];   // [k][c]
  float acc[4][4] = {{0.f}};
  for (int k0 = 0; k0 < HID; k0 += 16) {
    __syncthreads();
    {
      const int o = tid >> 2, koff = (tid & 3) << 2;
      const float4 w4 = *(const float4*)(Wo + (size_t)(o0 + o) * HID + k0 + koff);
      wo_s[(koff + 0) * 68 + o] = w4.x;
      wo_s[(koff + 1) * 68 + o] = w4.y;
      wo_s[(koff + 2) * 68 + o] = w4.z;
      wo_s[(koff + 3) * 68 + o] = w4.w;
      const int kk = tid >> 4, cc = (tid & 15) << 2;
      *(float4*)(a_s + kk * 68 + cc) =
          *(const float4*)(A + ((size_t)b * HID + k0 + kk) * C + c0 + cc);
    }
    __syncthreads();
#pragma unroll
    for (int kc = 0; kc < 16; ++kc) {
      const float4 wv = *(const float4*)(wo_s + kc * 68 + ty * 4);
      const float4 av = *(const float4*)(a_s + kc * 68 + tx * 4);
      const float b0 = av.x, b1 = av.y, b2 = av.z, b3 = av.w;
      acc[0][0] += wv.x * b0; acc[0][1] += wv.x * b1; acc[0][2] += wv.x * b2; acc[0][3] += wv.x * b3;
      acc[1][0] += wv.y * b0; acc[1][1] += wv.y * b1; acc[1][2] += wv.y * b2; acc[1][3] += wv.y * b3;
      acc[2][0] += wv.z * b0; acc[2][1] += wv.z * b1; acc[2][2] += wv.z * b2; acc[2][3] += wv.z * b3;
      acc[3][0] += wv.w * b0; acc[3][1] += wv.w * b1; acc[3][2] += wv.w * b2; acc[3][3] += wv.w * b3;
    }
  }
#pragma unroll
  for (int i = 0; i < 4; ++i) {
    ushort4 r;
    r.x = f2bf(acc[i][0]); r.y = f2bf(acc[i][1]);
    r.z = f2bf(acc[i][2]); r.w = f2bf(acc[i][3]);
    *(ushort4*)(M_bf + ((size_t)b * C + o0 + ty * 4 + i) * C + c0 + tx * 4) = r;
  }
}

// ---------------------------------------------------------------------------
// Kernel 4 (MFMA): out[b] = M_b (256x256) @ X_b (256x4096) + bo
// ---------------------------------------------------------------------------
__global__ __launch_bounds__(256) void out_mfma_kernel(
    const ushort* __restrict__ M_bf,     // [B][C][C] bf16
    const ushort* __restrict__ x_bf,     // [B][N][C] bf16
    const float* __restrict__ bo, float* __restrict__ out)
{
  const int nt = blockIdx.x, ot = blockIdx.y, b = blockIdx.z;
  const int tid = threadIdx.x;
  const int w = tid >> 6, lane = tid & 63;
  const int col = lane & 15, quad = lane >> 4;
  const int o0 = ot * 64;
  const size_t n_base = (size_t)nt * 256 + w * 64;
  const ushort* Ab = M_bf + ((size_t)b * C + o0 + col) * C + quad * 8;
  const ushort* Bb = x_bf + ((size_t)b * N + n_base) * C + quad * 8;

  const f32x4 z4 = {0.f, 0.f, 0.f, 0.f};
  f32x4 acc[4][4];
#pragma unroll
  for (int i = 0; i < 4; ++i)
#pragma unroll
    for (int j = 0; j < 4; ++j) acc[i][j] = z4;

#pragma unroll
  for (int kk = 0; kk < 8; ++kk) {
    bf16x8 af[4], bfz[4];
#pragma unroll
    for (int i = 0; i < 4; ++i) af[i] = *(const bf16x8*)(Ab + (size_t)(i * 16) * C + kk * 32);
#pragma unroll
    for (int j = 0; j < 4; ++j) bfz[j] = *(const bf16x8*)(Bb + (size_t)(j * 16 + col) * C + kk * 32);
#pragma unroll
    for (int i = 0; i < 4; ++i)
#pragma unroll
      for (int j = 0; j < 4; ++j) acc[i][j] = mfma16(af[i], bfz[j], acc[i][j]);
  }

#pragma unroll
  for (int i = 0; i < 4; ++i)
#pragma unroll
    for (int r = 0; r < 4; ++r) {
      const int o = o0 + i * 16 + quad * 4 + r;
      const float bias = bo[o];
      float* op = out + ((size_t)b * C + o) * N + n_base + col;
#pragma unroll
      for (int j = 0; j < 4; ++j) op[j * 16] = acc[i][j][r] + bias;
    }
}

// ---------------------------------------------------------------------------
extern "C" void kernel_launch(void* const* d_in, const int* in_sizes, int n_in,
                              void* d_out, int out_size, void* d_ws, size_t ws_size,
                              hipStream_t stream) {
  const float* x    = (const float*)d_in[0];
  const float* ctxt = (const float*)d_in[1];
  const float* Wq   = (const float*)d_in[2];
  const float* Wk   = (const float*)d_in[3];
  const float* Wv   = (const float*)d_in[4];
  const float* Wo   = (const float*)d_in[5];
  const float* bo   = (const float*)d_in[6];
  float* out = (float*)d_out;

  char* p = (char*)d_ws;
  ushort* ctxt_bf = (ushort*)p;  p += (size_t)B * N * C * 2;   // 16 MB (x_bf aliases)
  ushort* wk_bf   = (ushort*)p;  p += (size_t)HID * C * 2;
  ushort* wv_bf   = (ushort*)p;  p += (size_t)HID * C * 2;
  ushort* M_bf    = (ushort*)p;  p += (size_t)B * C * C * 2;
  float*  ctx_acc = (float*)p;   p += (size_t)B * H * D * D * 4;
  float*  z_acc   = (float*)p;   p += (size_t)B * H * D * 4;
  float*  ctxn    = (float*)p;   p += (size_t)B * H * D * D * 4;
  float*  A       = (float*)p;   p += (size_t)B * HID * C * 4;
  ushort* x_bf    = ctxt_bf;     // reused after kv_mfma_kernel

  hipMemsetAsync(ctx_acc, 0, (size_t)B * H * D * D * 4 + (size_t)B * H * D * 4, stream);
  cast_w_kernel<<<dim3(HID * C / 1024), 256, 0, stream>>>(Wk, Wv, wk_bf, wv_bf);
  transpose_cast_kernel<<<dim3(N / 64, C / 64, B), 256, 0, stream>>>(ctxt, ctxt_bf, C, N);
  kv_mfma_kernel<<<dim3(N / 256, H, B), 256, 0, stream>>>(ctxt_bf, wk_bf, wv_bf, ctx_acc, z_acc);
  transpose_cast_kernel<<<dim3(N / 64, C / 64, B), 256, 0, stream>>>(x, x_bf, C, N);
  combine_kernel<<<dim3(B * H), 256, 0, stream>>>(ctx_acc, z_acc, ctxn);
  a_kernel<<<dim3(B * H), 256, 0, stream>>>(ctxn, Wq, A);
  m_kernel<<<dim3(16, B), 256, 0, stream>>>(A, Wo, M_bf);
  out_mfma_kernel<<<dim3(N / 256, C / 64, B), 256, 0, stream>>>(M_bf, x_bf, bo, out);
}

// Round 3
// 255.392 us; speedup vs baseline: 2.1431x; 1.1901x over previous
//
#include <hip/hip_runtime.h>

#define B   8
#define C   256
#define N   4096
#define H   8
#define D   64
#define HID 512
#define SCALE 0.125f

typedef __attribute__((ext_vector_type(8))) __bf16 bf16x8;
typedef __attribute__((ext_vector_type(4))) float f32x4;

__device__ __forceinline__ ushort f2bf(float f) {
  union { float f; unsigned u; } v; v.f = f;
  unsigned r = v.u + 0x7FFFu + ((v.u >> 16) & 1u);
  return (ushort)(r >> 16);
}

__device__ __forceinline__ f32x4 mfma16(bf16x8 a, bf16x8 b, f32x4 c) {
  return __builtin_amdgcn_mfma_f32_16x16x32_bf16(a, b, c, 0, 0, 0);
}

// ---------------------------------------------------------------------------
// Cast Wk, Wv to bf16 (row-major [HID][C] kept).
// ---------------------------------------------------------------------------
__global__ __launch_bounds__(256) void cast_w_kernel(
    const float* __restrict__ Wk, const float* __restrict__ Wv,
    ushort* __restrict__ wk_bf, ushort* __restrict__ wv_bf) {
  const int t = (blockIdx.x * 256 + threadIdx.x) * 4;   // HID*C = 131072 elems
  const float4 a = *(const float4*)(Wk + t);
  const float4 b = *(const float4*)(Wv + t);
  ushort4 ra, rb;
  ra.x = f2bf(a.x); ra.y = f2bf(a.y); ra.z = f2bf(a.z); ra.w = f2bf(a.w);
  rb.x = f2bf(b.x); rb.y = f2bf(b.y); rb.z = f2bf(b.z); rb.w = f2bf(b.w);
  *(ushort4*)(wk_bf + t) = ra;
  *(ushort4*)(wv_bf + t) = rb;
}

// ---------------------------------------------------------------------------
// Transpose+cast: src fp32 [b][R][L] -> dst bf16 [b][L][R].  64x64 tiles.
// ---------------------------------------------------------------------------
__global__ __launch_bounds__(256) void transpose_cast_kernel(
    const float* __restrict__ src, ushort* __restrict__ dst, int R, int L) {
  __shared__ float tile[64 * 65];
  const int l0 = blockIdx.x * 64, r0 = blockIdx.y * 64, b = blockIdx.z;
  const int tid = threadIdx.x;
  const int rr = tid >> 4, c4 = (tid & 15) << 2;
  const float* sp = src + ((size_t)b * R + r0) * L + l0;
#pragma unroll
  for (int p = 0; p < 4; ++p) {
    const float4 v = *(const float4*)(sp + (size_t)(rr + p * 16) * L + c4);
    float* tp = tile + (rr + p * 16) * 65 + c4;
    tp[0] = v.x; tp[1] = v.y; tp[2] = v.z; tp[3] = v.w;
  }
  __syncthreads();
  const int lr = tid >> 2, rb = (tid & 3) << 4;
  uint pk[8];
#pragma unroll
  for (int k = 0; k < 16; k += 2) {
    const uint lo = f2bf(tile[(rb + k) * 65 + lr]);
    const uint hi = f2bf(tile[(rb + k + 1) * 65 + lr]);
    pk[k >> 1] = lo | (hi << 16);
  }
  ushort* dp = dst + ((size_t)b * L + l0 + lr) * R + r0 + rb;
  *(uint4*)dp = *(uint4*)pk;
  *(uint4*)(dp + 8) = *(uint4*)(pk + 4);
}

// ---------------------------------------------------------------------------
// Kernel 1 (MFMA): per (m-chunk of 256, h, b):
//   K^T = C_b^T @ Wk_h^T  (A = ctxt rows m, B = Wk rows d)  -> D[m][d]
//   P = exp(K); V^T likewise; ctx[d][e] = sum_m P V; Z[d] = rowsum(P)
// Each wave owns a 64-m quarter.  P/V staged via b64 writes / b128 reads
// (XOR swizzle).  One barrier; per-mt partials, no atomics.
// ---------------------------------------------------------------------------
__global__ __launch_bounds__(256, 2) void kv_mfma_kernel(
    const ushort* __restrict__ ctxt_bf,   // [B][N][C] bf16
    const ushort* __restrict__ wk_bf,     // [HID][C]
    const ushort* __restrict__ wv_bf,
    float* __restrict__ ctx_part,         // [B*H][16][64*64]  ([e][d])
    float* __restrict__ z_part)           // [B*H][16][64]
{
  __shared__ __align__(16) ushort pv[4 * 2 * 64 * 64];   // 64 KB
  __shared__ float zred[4][64];
  const int mt = blockIdx.x, h = blockIdx.y, b = blockIdx.z;
  const int tid = threadIdx.x;
  const int w = tid >> 6, lane = tid & 63;
  const int col = lane & 15, quad = lane >> 4;

  const size_t m_base = (size_t)mt * 256 + w * 64;
  const ushort* cb  = ctxt_bf + ((size_t)b * N + m_base) * C;
  const ushort* wkp = wk_bf + (size_t)(h * 64) * C;
  const ushort* wvp = wv_bf + (size_t)(h * 64) * C;

  const f32x4 z4 = {0.f, 0.f, 0.f, 0.f};

  // ---- merged K+V projection: D[m][d] ----
  f32x4 kacc[4][4], vacc[4][4];
#pragma unroll
  for (int i = 0; i < 4; ++i)
#pragma unroll
    for (int j = 0; j < 4; ++j) { kacc[i][j] = z4; vacc[i][j] = z4; }
#pragma unroll
  for (int kk = 0; kk < 8; ++kk) {
    const int ko = kk * 32 + quad * 8;
    bf16x8 a[4], bk[4], bv[4];
#pragma unroll
    for (int i = 0; i < 4; ++i) a[i] = *(const bf16x8*)(cb + (size_t)(i * 16 + col) * C + ko);
#pragma unroll
    for (int j = 0; j < 4; ++j) bk[j] = *(const bf16x8*)(wkp + (size_t)(j * 16 + col) * C + ko);
#pragma unroll
    for (int j = 0; j < 4; ++j) bv[j] = *(const bf16x8*)(wvp + (size_t)(j * 16 + col) * C + ko);
#pragma unroll
    for (int i = 0; i < 4; ++i)
#pragma unroll
      for (int j = 0; j < 4; ++j) {
        kacc[i][j] = mfma16(a[i], bk[j], kacc[i][j]);
        vacc[i][j] = mfma16(a[i], bv[j], vacc[i][j]);
      }
  }

  // ---- exp + vectorized staging (b64 writes), Z partials ----
  ushort* wp   = pv + w * 8192;        // P: [d][m64] swizzled, 8 KB
  ushort* wvs  = wp + 4096;            // V: [e][m64] swizzled, 8 KB
  float zl[4] = {0.f, 0.f, 0.f, 0.f};
#pragma unroll
  for (int i = 0; i < 4; ++i) {
    const int g = i * 2 + (quad >> 1);       // m>>3 group
    const int sub = (quad & 1) << 2;         // m&7 sub-offset
#pragma unroll
    for (int j = 0; j < 4; ++j) {
      const int d = j * 16 + col;
      const int off = d * 64 + (((g ^ (col & 7)) << 3) | sub);
      const f32x4 k4 = kacc[i][j];
      const float e0 = __expf(k4[0]), e1 = __expf(k4[1]);
      const float e2 = __expf(k4[2]), e3 = __expf(k4[3]);
      zl[j] += (e0 + e1) + (e2 + e3);
      ushort4 pk; pk.x = f2bf(e0); pk.y = f2bf(e1); pk.z = f2bf(e2); pk.w = f2bf(e3);
      const f32x4 v4 = vacc[i][j];
      ushort4 vk; vk.x = f2bf(v4[0]); vk.y = f2bf(v4[1]); vk.z = f2bf(v4[2]); vk.w = f2bf(v4[3]);
      *(ushort4*)(wp + off) = pk;
      *(ushort4*)(wvs + off) = vk;
    }
  }
#pragma unroll
  for (int j = 0; j < 4; ++j) {
    float s = zl[j];
    s += __shfl_xor(s, 16); s += __shfl_xor(s, 32);
    if (quad == 0) zred[w][j * 16 + col] = s;
  }

  // ---- ctx = P V^T over this wave's 64 m (reads own LDS region only) ----
  f32x4 cacc[4][4];
#pragma unroll
  for (int i = 0; i < 4; ++i)
#pragma unroll
    for (int j = 0; j < 4; ++j) cacc[i][j] = z4;
#pragma unroll
  for (int kk = 0; kk < 2; ++kk) {
    const int swz = ((kk * 4 + quad) ^ (col & 7)) << 3;
    bf16x8 pa[4], vb[4];
#pragma unroll
    for (int i = 0; i < 4; ++i) pa[i] = *(const bf16x8*)(wp + (i * 16 + col) * 64 + swz);
#pragma unroll
    for (int j = 0; j < 4; ++j) vb[j] = *(const bf16x8*)(wvs + (j * 16 + col) * 64 + swz);
#pragma unroll
    for (int i = 0; i < 4; ++i)
#pragma unroll
      for (int j = 0; j < 4; ++j) cacc[i][j] = mfma16(pa[i], vb[j], cacc[i][j]);
  }

  // ---- per-wave cacc -> own LDS region as fp32 [e][d] (b128, swizzled) ----
  float* cred = (float*)pv + w * 4096;
#pragma unroll
  for (int i = 0; i < 4; ++i)
#pragma unroll
    for (int j = 0; j < 4; ++j) {
      const int e = j * 16 + col;
      const int off = e * 64 + ((((i * 4 + quad) ^ col)) << 2);
      *(f32x4*)(cred + off) = cacc[i][j];
    }
  __syncthreads();

  // ---- cross-wave sum -> global partials (coalesced, no atomics) ----
  const int bh = b * H + h;
  float* outp = ctx_part + ((size_t)bh * 16 + mt) * 4096;
  const float* r0 = (const float*)pv;
#pragma unroll
  for (int k = 0; k < 4; ++k) {
    const int g = tid + k * 256;             // float4 group: 0..1023
    const int e = g >> 4, dg = g & 15;
    const int off = e * 64 + ((dg ^ (e & 15)) << 2);
    f32x4 s = *(const f32x4*)(r0 + off);
    s += *(const f32x4*)(r0 + 4096 + off);
    s += *(const f32x4*)(r0 + 8192 + off);
    s += *(const f32x4*)(r0 + 12288 + off);
    *(f32x4*)(outp + g * 4) = s;
  }
  if (tid < 64)
    z_part[((size_t)bh * 16 + mt) * 64 + tid] =
        (zred[0][tid] + zred[1][tid]) + (zred[2][tid] + zred[3][tid]);
}

// ---------------------------------------------------------------------------
// Kernel 2: sum partials, normalize cols by Z, fold in scale.  ctxn is [e][d].
// ---------------------------------------------------------------------------
__global__ __launch_bounds__(256) void combine_kernel(
    const float* __restrict__ ctx_part, const float* __restrict__ z_part,
    float* __restrict__ ctxn)            // [B*H][64(e)][64(d)]
{
  const int bh = blockIdx.x, tid = threadIdx.x;
  __shared__ float zs[64];
  if (tid < 64) {
    float z = 0.f;
    for (int p = 0; p < 16; ++p) z += z_part[((size_t)bh * 16 + p) * 64 + tid];
    zs[tid] = SCALE / z;
  }
  __syncthreads();
  const float* cp = ctx_part + (size_t)bh * 16 * 4096;
  for (int k = 0; k < 16; ++k) {
    const int idx = tid + (k << 8);
    float s = 0.f;
    for (int p = 0; p < 16; ++p) s += cp[(size_t)p * 4096 + idx];
    ctxn[((size_t)bh << 12) + idx] = s * zs[idx & 63];
  }
}

// ---------------------------------------------------------------------------
// Kernel 3a: A[b][h*64+e][c] = sum_d ctxn[b,h][e][d] * Wq[h*64+d, c]   (fp32)
// ---------------------------------------------------------------------------
__global__ __launch_bounds__(256) void a_kernel(
    const float* __restrict__ ctxn, const float* __restrict__ Wq,
    float* __restrict__ A)               // [B][HID][C]
{
  const int bh = blockIdx.x, tid = threadIdx.x;
  const int b = bh >> 3, h = bh & 7;
  __shared__ float ct[64 * 65];   // [e][d]
  __shared__ float wq[64 * 68];   // [d][c-tile]
  for (int r = 0; r < 16; ++r) {
    const int idx = tid + (r << 8);
    ct[(idx >> 6) * 65 + (idx & 63)] = ctxn[((size_t)bh << 12) + idx];
  }
  const int e = tid & 63, co = tid >> 6;
  for (int cti = 0; cti < 4; ++cti) {
    const int c0 = cti << 6;
    __syncthreads();
    for (int r = 0; r < 16; ++r) {
      const int idx = tid + (r << 8);
      wq[(idx >> 6) * 68 + (idx & 63)] =
          Wq[(size_t)(h * 64 + (idx >> 6)) * C + c0 + (idx & 63)];
    }
    __syncthreads();
    float acc[16];
#pragma unroll
    for (int k = 0; k < 16; ++k) acc[k] = 0.f;
    for (int d = 0; d < 64; ++d) {
      const float cv = ct[e * 65 + d];
      const float* wr = wq + d * 68 + co * 16;
#pragma unroll
      for (int k = 0; k < 16; ++k) acc[k] += cv * wr[k];
    }
    float* Ar = A + ((size_t)b * HID + h * 64 + e) * C + c0 + co * 16;
#pragma unroll
    for (int k = 0; k < 16; ++k) Ar[k] = acc[k];
  }
}

// ---------------------------------------------------------------------------
// Kernel 3b: M[b] = Wo (256x512) @ A[b] (512x256)  -> bf16 [b][o][c]
// ---------------------------------------------------------------------------
__global__ __launch_bounds__(256) void m_kernel(
    const float* __restrict__ A, const float* __restrict__ Wo,
    ushort* __restrict__ M_bf)
{
  const int tile = blockIdx.x, b = blockIdx.y;
  const int o0 = (tile & 3) << 6, c0 = (tile >> 2) << 6;
  const int tid = threadIdx.x, tx = tid & 15, ty = tid >> 4;
  __shared__ float wo_s[16 * 68];  // [k][o]
  __shared__ float a_s[16 * 68];   // [k][c]
  float acc[4][4] = {{0.f}};
  for (int k0 = 0; k0 < HID; k0 += 16) {
    __syncthreads();
    {
      const int o = tid >> 2, koff = (tid & 3) << 2;
      const float4 w4 = *(const float4*)(Wo + (size_t)(o0 + o) * HID + k0 + koff);
      wo_s[(koff + 0) * 68 + o] = w4.x;
      wo_s[(koff + 1) * 68 + o] = w4.y;
      wo_s[(koff + 2) * 68 + o] = w4.z;
      wo_s[(koff + 3) * 68 + o] = w4.w;
      const int kk = tid >> 4, cc = (tid & 15) << 2;
      *(float4*)(a_s + kk * 68 + cc) =
          *(const float4*)(A + ((size_t)b * HID + k0 + kk) * C + c0 + cc);
    }
    __syncthreads();
#pragma unroll
    for (int kc = 0; kc < 16; ++kc) {
      const float4 wv = *(const float4*)(wo_s + kc * 68 + ty * 4);
      const float4 av = *(const float4*)(a_s + kc * 68 + tx * 4);
      const float b0 = av.x, b1 = av.y, b2 = av.z, b3 = av.w;
      acc[0][0] += wv.x * b0; acc[0][1] += wv.x * b1; acc[0][2] += wv.x * b2; acc[0][3] += wv.x * b3;
      acc[1][0] += wv.y * b0; acc[1][1] += wv.y * b1; acc[1][2] += wv.y * b2; acc[1][3] += wv.y * b3;
      acc[2][0] += wv.z * b0; acc[2][1] += wv.z * b1; acc[2][2] += wv.z * b2; acc[2][3] += wv.z * b3;
      acc[3][0] += wv.w * b0; acc[3][1] += wv.w * b1; acc[3][2] += wv.w * b2; acc[3][3] += wv.w * b3;
    }
  }
#pragma unroll
  for (int i = 0; i < 4; ++i) {
    ushort4 r;
    r.x = f2bf(acc[i][0]); r.y = f2bf(acc[i][1]);
    r.z = f2bf(acc[i][2]); r.w = f2bf(acc[i][3]);
    *(ushort4*)(M_bf + ((size_t)b * C + o0 + ty * 4 + i) * C + c0 + tx * 4) = r;
  }
}

// ---------------------------------------------------------------------------
// Kernel 4 (MFMA): out[b] = M_b (256x256) @ X_b (256x4096) + bo
// ---------------------------------------------------------------------------
__global__ __launch_bounds__(256) void out_mfma_kernel(
    const ushort* __restrict__ M_bf,     // [B][C][C] bf16
    const ushort* __restrict__ x_bf,     // [B][N][C] bf16
    const float* __restrict__ bo, float* __restrict__ out)
{
  const int nt = blockIdx.x, ot = blockIdx.y, b = blockIdx.z;
  const int tid = threadIdx.x;
  const int w = tid >> 6, lane = tid & 63;
  const int col = lane & 15, quad = lane >> 4;
  const int o0 = ot * 64;
  const size_t n_base = (size_t)nt * 256 + w * 64;
  const ushort* Ab = M_bf + ((size_t)b * C + o0 + col) * C + quad * 8;
  const ushort* Bb = x_bf + ((size_t)b * N + n_base) * C + quad * 8;

  const f32x4 z4 = {0.f, 0.f, 0.f, 0.f};
  f32x4 acc[4][4];
#pragma unroll
  for (int i = 0; i < 4; ++i)
#pragma unroll
    for (int j = 0; j < 4; ++j) acc[i][j] = z4;

#pragma unroll
  for (int kk = 0; kk < 8; ++kk) {
    bf16x8 af[4], bfz[4];
#pragma unroll
    for (int i = 0; i < 4; ++i) af[i] = *(const bf16x8*)(Ab + (size_t)(i * 16) * C + kk * 32);
#pragma unroll
    for (int j = 0; j < 4; ++j) bfz[j] = *(const bf16x8*)(Bb + (size_t)(j * 16 + col) * C + kk * 32);
#pragma unroll
    for (int i = 0; i < 4; ++i)
#pragma unroll
      for (int j = 0; j < 4; ++j) acc[i][j] = mfma16(af[i], bfz[j], acc[i][j]);
  }

#pragma unroll
  for (int i = 0; i < 4; ++i)
#pragma unroll
    for (int r = 0; r < 4; ++r) {
      const int o = o0 + i * 16 + quad * 4 + r;
      const float bias = bo[o];
      float* op = out + ((size_t)b * C + o) * N + n_base + col;
#pragma unroll
      for (int j = 0; j < 4; ++j) op[j * 16] = acc[i][j][r] + bias;
    }
}

// ---------------------------------------------------------------------------
extern "C" void kernel_launch(void* const* d_in, const int* in_sizes, int n_in,
                              void* d_out, int out_size, void* d_ws, size_t ws_size,
                              hipStream_t stream) {
  const float* x    = (const float*)d_in[0];
  const float* ctxt = (const float*)d_in[1];
  const float* Wq   = (const float*)d_in[2];
  const float* Wk   = (const float*)d_in[3];
  const float* Wv   = (const float*)d_in[4];
  const float* Wo   = (const float*)d_in[5];
  const float* bo   = (const float*)d_in[6];
  float* out = (float*)d_out;

  char* p = (char*)d_ws;
  ushort* ctxt_bf = (ushort*)p;  p += (size_t)B * N * C * 2;        // 16 MB (x_bf aliases)
  ushort* wk_bf   = (ushort*)p;  p += (size_t)HID * C * 2;
  ushort* wv_bf   = (ushort*)p;  p += (size_t)HID * C * 2;
  ushort* M_bf    = (ushort*)p;  p += (size_t)B * C * C * 2;
  float*  z_part  = (float*)p;   p += (size_t)B * H * 16 * 64 * 4;
  float*  ctxn    = (float*)p;   p += (size_t)B * H * D * D * 4;
  float*  ctx_part= (float*)p;   p += (size_t)B * H * 16 * 4096 * 4; // 16.8 MB
  float*  A       = ctx_part;    // aliased: ctx_part dead after combine_kernel
  ushort* x_bf    = ctxt_bf;     // reused after kv_mfma_kernel

  cast_w_kernel<<<dim3(HID * C / 1024), 256, 0, stream>>>(Wk, Wv, wk_bf, wv_bf);
  transpose_cast_kernel<<<dim3(N / 64, C / 64, B), 256, 0, stream>>>(ctxt, ctxt_bf, C, N);
  kv_mfma_kernel<<<dim3(16, H, B), 256, 0, stream>>>(ctxt_bf, wk_bf, wv_bf, ctx_part, z_part);
  transpose_cast_kernel<<<dim3(N / 64, C / 64, B), 256, 0, stream>>>(x, x_bf, C, N);
  combine_kernel<<<dim3(B * H), 256, 0, stream>>>(ctx_part, z_part, ctxn);
  a_kernel<<<dim3(B * H), 256, 0, stream>>>(ctxn, Wq, A);
  m_kernel<<<dim3(16, B), 256, 0, stream>>>(A, Wo, M_bf);
  out_mfma_kernel<<<dim3(N / 256, C / 64, B), 256, 0, stream>>>(M_bf, x_bf, bo, out);
}